// Round 1
// baseline (331.307 us; speedup 1.0000x reference)
//
#include <hip/hip_runtime.h>
#include <stdint.h>

#define GENOMES 8
#define BATCH 2
#define SEQ 2048
#define EMBED 1024
#define KVD 256              // KV_HEADS * HEAD_DIM
#define M_PER_G (BATCH*SEQ)  // 4096

typedef float f32x4 __attribute__((ext_vector_type(4)));
typedef __bf16 bf16x8 __attribute__((ext_vector_type(8)));
typedef short s16x8 __attribute__((ext_vector_type(8)));
typedef short s16x4 __attribute__((ext_vector_type(4)));

static __device__ __forceinline__ unsigned short f2bf(float f) {
  unsigned int u = __builtin_bit_cast(unsigned int, f);
  u += 0x7FFFu + ((u >> 16) & 1u);   // round-to-nearest-even
  return (unsigned short)(u >> 16);
}

// ---------------------------------------------------------------------------
// Wv (g, 1024, 256) fp32  ->  WvT (g, 256, 1024) bf16   (B^T layout for GEMM1)
// ---------------------------------------------------------------------------
__global__ __launch_bounds__(256) void wvt_kernel(const float* __restrict__ Wv,
                                                  unsigned short* __restrict__ WvT) {
  int g = blockIdx.y;
  int it = blockIdx.x >> 2;          // 16 i-tiles of 64
  int ot = blockIdx.x & 3;           // 4 o-tiles of 64
  int i0 = it * 64, o0 = ot * 64;
  const float* W = Wv + (size_t)g * EMBED * KVD;
  unsigned short* T = WvT + (size_t)g * KVD * EMBED;
  __shared__ unsigned short tl[64][65];
  int t = threadIdx.x;
  int rr = t >> 4;            // 0..15
  int cc = (t & 15) * 4;      // 0..60
#pragma unroll
  for (int p = 0; p < 4; ++p) {
    int r = rr + p * 16;
    float4 v = *(const float4*)(W + (size_t)(i0 + r) * KVD + o0 + cc);
    tl[r][cc + 0] = f2bf(v.x);
    tl[r][cc + 1] = f2bf(v.y);
    tl[r][cc + 2] = f2bf(v.z);
    tl[r][cc + 3] = f2bf(v.w);
  }
  __syncthreads();
#pragma unroll
  for (int p = 0; p < 4; ++p) {
    int o = rr + p * 16;
    s16x4 v;
    v[0] = (short)tl[cc + 0][o];
    v[1] = (short)tl[cc + 1][o];
    v[2] = (short)tl[cc + 2][o];
    v[3] = (short)tl[cc + 3][o];
    *(s16x4*)(T + (size_t)(o0 + o) * EMBED + i0 + cc) = v;
  }
}

// ---------------------------------------------------------------------------
// Wo (g, 1024, 1024) fp32 -> RT (g, 1024, 256) bf16
// RT[o][kh*64+d] = 64 * sum_{r=0..3} Wo[kh*256 + r*64 + d][o]
// (head-broadcast folded into Wo, x64 softmax-sum factor folded in, transposed)
// ---------------------------------------------------------------------------
__global__ __launch_bounds__(256) void rt_kernel(const float* __restrict__ Wo,
                                                 unsigned short* __restrict__ RT) {
  int g = blockIdx.y;
  int ot = blockIdx.x >> 2;          // 16 o-tiles of 64
  int kh = blockIdx.x & 3;           // 4 kv heads
  int o0 = ot * 64;
  const float* W = Wo + (size_t)g * EMBED * EMBED;
  unsigned short* T = RT + (size_t)g * EMBED * KVD;
  __shared__ float tl[64][65];
  int t = threadIdx.x;
  int rr = t >> 4;
  int cc = (t & 15) * 4;
#pragma unroll
  for (int p = 0; p < 4; ++p) {
    int d = rr + p * 16;
    float a0 = 0.f, a1 = 0.f, a2 = 0.f, a3 = 0.f;
#pragma unroll
    for (int r = 0; r < 4; ++r) {
      float4 v = *(const float4*)(W + (size_t)(kh * 256 + r * 64 + d) * EMBED + o0 + cc);
      a0 += v.x; a1 += v.y; a2 += v.z; a3 += v.w;
    }
    tl[d][cc + 0] = a0; tl[d][cc + 1] = a1; tl[d][cc + 2] = a2; tl[d][cc + 3] = a3;
  }
  __syncthreads();
#pragma unroll
  for (int p = 0; p < 4; ++p) {
    int o = rr + p * 16;
    s16x4 v;
    v[0] = (short)f2bf(64.f * tl[cc + 0][o]);
    v[1] = (short)f2bf(64.f * tl[cc + 1][o]);
    v[2] = (short)f2bf(64.f * tl[cc + 2][o]);
    v[3] = (short)f2bf(64.f * tl[cc + 3][o]);
    *(s16x4*)(T + (size_t)(o0 + o) * KVD + kh * 64 + cc) = v;
  }
}

// ---------------------------------------------------------------------------
// C[M,N] = A[M,K] * Bt[N,K]^T   (per genome in blockIdx.y)
// A: fp32 (converted to bf16 in staging) or bf16; Bt: bf16; C: bf16 or fp32
// 128x128 tile, BK=32, 256 threads (4 waves, 2x2 of 64x64), 16x16x32 MFMA
// ---------------------------------------------------------------------------
template <bool A_F32, bool OUT_BF16, int M, int N, int K>
__global__ __launch_bounds__(256) void gemm_bt(const void* __restrict__ Aall,
                                               const unsigned short* __restrict__ Btall,
                                               void* __restrict__ Call) {
  constexpr int BK = 32;
  int g = blockIdx.y;
  constexpr int NTILES = N / 128;
  int bm = blockIdx.x / NTILES;
  int bn = blockIdx.x % NTILES;
  int m0 = bm * 128, n0 = bn * 128;
  const unsigned short* Bt = Btall + (size_t)g * N * K;
  const float* Af = (const float*)Aall + (size_t)g * M * K;
  const unsigned short* Ab = (const unsigned short*)Aall + (size_t)g * M * K;

  __shared__ unsigned short As[128][BK];
  __shared__ unsigned short Bs[128][BK];

  int t = threadIdx.x;
  int lane = t & 63, wave = t >> 6;
  int wm = (wave >> 1) * 64, wn = (wave & 1) * 64;
  int lm = lane & 15, quad = lane >> 4;
  int kq = quad * 8;

  f32x4 acc[4][4] = {};

  for (int k0 = 0; k0 < K; k0 += BK) {
    // ---- stage A tile (128 x 32) ----
    if constexpr (A_F32) {
      int row = t >> 3, col = (t & 7) * 4;
#pragma unroll
      for (int p = 0; p < 4; ++p) {
        int r = row + p * 32;
        float4 v = *(const float4*)(Af + (size_t)(m0 + r) * K + k0 + col);
        s16x4 b;
        b[0] = (short)f2bf(v.x); b[1] = (short)f2bf(v.y);
        b[2] = (short)f2bf(v.z); b[3] = (short)f2bf(v.w);
        *(s16x4*)&As[r][col] = b;
      }
    } else {
      int row = t >> 2, col = (t & 3) * 8;
#pragma unroll
      for (int p = 0; p < 2; ++p) {
        int r = row + p * 64;
        s16x8 v = *(const s16x8*)(Ab + (size_t)(m0 + r) * K + k0 + col);
        *(s16x8*)&As[r][col] = v;
      }
    }
    // ---- stage B tile (128 x 32) ----
    {
      int row = t >> 2, col = (t & 3) * 8;
#pragma unroll
      for (int p = 0; p < 2; ++p) {
        int r = row + p * 64;
        s16x8 v = *(const s16x8*)(Bt + (size_t)(n0 + r) * K + k0 + col);
        *(s16x8*)&Bs[r][col] = v;
      }
    }
    __syncthreads();

    // ---- 16 MFMAs ----
    bf16x8 af[4], bfr[4];
#pragma unroll
    for (int i = 0; i < 4; ++i) {
      af[i]  = __builtin_bit_cast(bf16x8, *(const s16x8*)&As[wm + i * 16 + lm][kq]);
      bfr[i] = __builtin_bit_cast(bf16x8, *(const s16x8*)&Bs[wn + i * 16 + lm][kq]);
    }
#pragma unroll
    for (int i = 0; i < 4; ++i)
#pragma unroll
      for (int j = 0; j < 4; ++j)
        acc[i][j] = __builtin_amdgcn_mfma_f32_16x16x32_bf16(af[i], bfr[j], acc[i][j], 0, 0, 0);
    __syncthreads();
  }

  // ---- epilogue: C/D layout col=lane&15, row=quad*4+reg ----
  if constexpr (OUT_BF16) {
    unsigned short* C = (unsigned short*)Call + (size_t)g * M * N;
#pragma unroll
    for (int i = 0; i < 4; ++i)
#pragma unroll
      for (int j = 0; j < 4; ++j)
#pragma unroll
        for (int r = 0; r < 4; ++r) {
          int mm = m0 + wm + i * 16 + quad * 4 + r;
          int nn = n0 + wn + j * 16 + lm;
          C[(size_t)mm * N + nn] = f2bf(acc[i][j][r]);
        }
  } else {
    float* C = (float*)Call + (size_t)g * M * N;
#pragma unroll
    for (int i = 0; i < 4; ++i)
#pragma unroll
      for (int j = 0; j < 4; ++j)
#pragma unroll
        for (int r = 0; r < 4; ++r) {
          int mm = m0 + wm + i * 16 + quad * 4 + r;
          int nn = n0 + wn + j * 16 + lm;
          C[(size_t)mm * N + nn] = acc[i][j][r];
        }
  }
}

// ---------------------------------------------------------------------------
extern "C" void kernel_launch(void* const* d_in, const int* in_sizes, int n_in,
                              void* d_out, int out_size, void* d_ws, size_t ws_size,
                              hipStream_t stream) {
  const float* tensor = (const float*)d_in[0];
  // d_in[1] = Wq, d_in[2] = Wk: dead code in the reference (einsum contracts them out)
  const float* Wv = (const float*)d_in[3];
  const float* Wo = (const float*)d_in[4];
  float* out = (float*)d_out;

  unsigned short* WvT = (unsigned short*)d_ws;                       //  4 MB
  unsigned short* RT  = WvT + (size_t)GENOMES * KVD * EMBED;         //  4 MB
  unsigned short* V   = RT  + (size_t)GENOMES * EMBED * KVD;         // 16 MB

  // prep: transpose/convert Wv, fold+transpose/convert Wo
  wvt_kernel<<<dim3(64, GENOMES), 256, 0, stream>>>(Wv, WvT);
  rt_kernel<<<dim3(64, GENOMES), 256, 0, stream>>>(Wo, RT);

  // GEMM1: V[g] (4096x256 bf16) = tensor[g] (4096x1024 fp32) @ WvT^T
  gemm_bt<true, true, M_PER_G, KVD, EMBED>
      <<<dim3((M_PER_G / 128) * (KVD / 128), GENOMES), 256, 0, stream>>>(tensor, WvT, V);

  // GEMM2: out[g] (4096x1024 fp32) = V[g] (4096x256 bf16) @ RT^T   (x64 folded into RT)
  gemm_bt<false, false, M_PER_G, EMBED, KVD>
      <<<dim3((M_PER_G / 128) * (EMBED / 128), GENOMES), 256, 0, stream>>>(V, RT, out);
}